// Round 4
// baseline (273.799 us; speedup 1.0000x reference)
//
#include <hip/hip_runtime.h>

// GCN block: h1 = ReLU(Agg(x@W1)+b1); h2 = ReLU(Agg(h1@W2)+b2); out = BN(h2)
// R19: (a) sentinel-padded buckets — pad slots [cnt_h, cnt_h+8) with sentinel
// node n whose feature row is zeroed; removes ALL mask/sanitize VALU and takes
// cnt off the gather critical path. (b) paired 2-node gathers: 16 concurrent
// row gathers per half-wave (two asm blocks, one vmcnt(0)) -> 2 nodes per
// latency step (~430cy/node vs ~750). Slot int4 prefetched one pair ahead;
// second int4 is same cache line (L1 hit). (c) k_agg_stats -> 512-thr blocks
// (softer VGPR cliff); k_agg_gemm forced to 8 waves/EU (VGPR<=64, 2 blk/CU).

#define D 128
#define CAP 96   // max in-degree capacity; E/N=12 mean, Poisson tail << 96

typedef __attribute__((ext_vector_type(8))) short bf16x8;
typedef __attribute__((ext_vector_type(4))) float f32x4;
typedef __attribute__((ext_vector_type(2))) unsigned u32x2;

__device__ inline float2 bf2x2(unsigned u) {
    float2 r;
    r.x = __uint_as_float(u << 16);
    r.y = __uint_as_float(u & 0xffff0000u);
    return r;
}
__device__ inline unsigned short f2bf(float f) {
    unsigned u = __float_as_uint(f);
    u += 0x7fffu + ((u >> 16) & 1u);   // round-to-nearest-even
    return (unsigned short)(u >> 16);
}

// ------- fused histogram+fill: one atomic per edge; + W transpose-convert -------
// Split-half bucket layout: slot s -> half s&1, index s>>1 (contiguous per half).
__global__ void k_histfill(const int* __restrict__ row, const int* __restrict__ col,
                           int* __restrict__ cnt, int* __restrict__ bucket, int E,
                           const float* __restrict__ W1, const float* __restrict__ W2,
                           unsigned short* __restrict__ Wt1,
                           unsigned short* __restrict__ Wt2) {
    int e = blockIdx.x * blockDim.x + threadIdx.x;
    if (e < E) {
        int c = col[e];
        int slot = atomicAdd(&cnt[c], 1);
        if (slot < CAP)
            bucket[(size_t)c * CAP + (slot & 1) * (CAP / 2) + (slot >> 1)] = row[e];
    }
    if (blockIdx.x < D) {
        int k = blockIdx.x;
        int t = threadIdx.x;
        if (t < D) Wt1[t * D + k] = f2bf(W1[k * D + t]);
        else       Wt2[(t - D) * D + k] = f2bf(W2[k * D + (t - D)]);
    }
}

// ------ 16-wave GEMM compute: wave w -> m-tile w>>1, n-half w&1 (4 n-tiles) ------
__device__ inline void gemm_compute16(const unsigned short* Xs, const unsigned short* Ws,
                                      const int* __restrict__ cnt,
                                      unsigned short* __restrict__ out, int n, int row0) {
    int tid = threadIdx.x;
    int w = tid >> 6;          // 0..15
    int wm = w >> 1;           // m-tile 0..7
    int wn = w & 1;            // n-half 0..1
    int lane = tid & 63;
    int m16 = lane & 15;
    int quad = lane >> 4;

    f32x4 acc[4];
#pragma unroll
    for (int u = 0; u < 4; u++) acc[u] = (f32x4){0.f, 0.f, 0.f, 0.f};

#pragma unroll
    for (int kc = 0; kc < 4; kc++) {
        bf16x8 a = *(const bf16x8*)&Xs[(wm * 16 + m16) * 136 + kc * 32 + quad * 8];
        bf16x8 b[4];
#pragma unroll
        for (int u = 0; u < 4; u++)
            b[u] = *(const bf16x8*)&Ws[((wn * 4 + u) * 16 + m16) * 136 + kc * 32 + quad * 8];
#pragma unroll
        for (int u = 0; u < 4; u++)
            acc[u] = __builtin_amdgcn_mfma_f32_16x16x32_bf16(a, b[u], acc[u], 0, 0, 0);
    }

    int rbase = row0 + wm * 16 + quad * 4;
#pragma unroll
    for (int i = 0; i < 4; i++) {
        int r = rbase + i;
        if (r < n) {
            float sc = rsqrtf((float)cnt[r] + 1.0f);
#pragma unroll
            for (int u = 0; u < 4; u++)
                out[(size_t)r * D + (wn * 4 + u) * 16 + m16] = f2bf(acc[u][i] * sc);
        }
    }
}

// -- GEMM1 (1024 thr, 16 waves): out[r] = bf16((X @ W)[r] * rsqrt(cnt[r]+1)) --
// R19: also sentinel-pads the bucket (slots [ch, ch+8) per node-half -> n).
__global__ __launch_bounds__(1024) void k_gemm1(
        const float* __restrict__ Xf, const unsigned short* __restrict__ Wt,
        const int* __restrict__ cnt, int* __restrict__ bucket,
        unsigned short* __restrict__ out, int n) {
    __shared__ unsigned short Xs[128 * 136];   // +8 pad: 2-way banks (free)
    __shared__ unsigned short Ws[128 * 136];
    int tid = threadIdx.x;
    int row0 = blockIdx.x * 128;

#pragma unroll
    for (int i = 0; i < 2; i++) {
        int c = tid + 1024 * i;
        int r = c >> 4;
        int kc = (c & 15) * 8;
        float4 va = {0.f, 0.f, 0.f, 0.f}, vb = {0.f, 0.f, 0.f, 0.f};
        if (row0 + r < n) {
            va = *(const float4*)&Xf[(size_t)(row0 + r) * D + kc];
            vb = *(const float4*)&Xf[(size_t)(row0 + r) * D + kc + 4];
        }
        ushort4 o0, o1;
        o0.x = f2bf(va.x); o0.y = f2bf(va.y); o0.z = f2bf(va.z); o0.w = f2bf(va.w);
        o1.x = f2bf(vb.x); o1.y = f2bf(vb.y); o1.z = f2bf(vb.z); o1.w = f2bf(vb.w);
        *(ushort4*)&Xs[r * 136 + kc] = o0;
        *(ushort4*)&Xs[r * 136 + kc + 4] = o1;
    }
#pragma unroll
    for (int i = 0; i < 2; i++) {
        int c = tid + 1024 * i;
        int r = c >> 4;
        int kc = (c & 15) * 8;
        uint4 v = *(const uint4*)&Wt[r * D + kc];
        *(uint4*)&Ws[r * 136 + kc] = v;
    }
    // sentinel pad: 128 nodes x 16 slot-writes, 2 per thread
#pragma unroll
    for (int q = 0; q < 2; q++) {
        int s = tid * 2 + q;
        int nl = s >> 4, sl = s & 15;
        int node = row0 + nl;
        if (node < n) {
            int mm = min(cnt[node], CAP);
            int hf = sl >> 3, kk = sl & 7;
            int j = ((mm - hf + 1) >> 1) + kk;
            if (j < CAP / 2)
                bucket[(size_t)node * CAP + hf * (CAP / 2) + j] = n;
        }
    }
    __syncthreads();
    gemm_compute16(Xs, Ws, cnt, out, n, row0);
}

// ---- forced-MLP gather: 8 concurrent row gathers (issue only, no wait) ----
struct G8 { u32x2 a, b, c, d, e, f, g, h; };

__device__ inline G8 issue8(const uint2* __restrict__ hs2,
                            unsigned o0, unsigned o1, unsigned o2, unsigned o3,
                            unsigned o4, unsigned o5, unsigned o6, unsigned o7) {
    G8 r;
    asm volatile(
        "global_load_dwordx2 %0, %8, %16\n\t"
        "global_load_dwordx2 %1, %9, %16\n\t"
        "global_load_dwordx2 %2, %10, %16\n\t"
        "global_load_dwordx2 %3, %11, %16\n\t"
        "global_load_dwordx2 %4, %12, %16\n\t"
        "global_load_dwordx2 %5, %13, %16\n\t"
        "global_load_dwordx2 %6, %14, %16\n\t"
        "global_load_dwordx2 %7, %15, %16"
        : "=&v"(r.a), "=&v"(r.b), "=&v"(r.c), "=&v"(r.d),
          "=&v"(r.e), "=&v"(r.f), "=&v"(r.g), "=&v"(r.h)
        : "v"(o0), "v"(o1), "v"(o2), "v"(o3),
          "v"(o4), "v"(o5), "v"(o6), "v"(o7),
          "s"(hs2));
    return r;
}

__device__ inline void wait_vm0() {
    asm volatile("s_waitcnt vmcnt(0)" ::: "memory");
    __builtin_amdgcn_sched_barrier(0);   // keep consumers below (rule: hipcc
                                         // hoists reg-only ops past asm waits)
}

__device__ inline void consume8(const G8& g, f32x4& A) {
    float2 x;
    x = bf2x2(g.a[0]); A[0] += x.x; A[1] += x.y;
    x = bf2x2(g.a[1]); A[2] += x.x; A[3] += x.y;
    x = bf2x2(g.b[0]); A[0] += x.x; A[1] += x.y;
    x = bf2x2(g.b[1]); A[2] += x.x; A[3] += x.y;
    x = bf2x2(g.c[0]); A[0] += x.x; A[1] += x.y;
    x = bf2x2(g.c[1]); A[2] += x.x; A[3] += x.y;
    x = bf2x2(g.d[0]); A[0] += x.x; A[1] += x.y;
    x = bf2x2(g.d[1]); A[2] += x.x; A[3] += x.y;
    x = bf2x2(g.e[0]); A[0] += x.x; A[1] += x.y;
    x = bf2x2(g.e[1]); A[2] += x.x; A[3] += x.y;
    x = bf2x2(g.f[0]); A[0] += x.x; A[1] += x.y;
    x = bf2x2(g.f[1]); A[2] += x.x; A[3] += x.y;
    x = bf2x2(g.g[0]); A[0] += x.x; A[1] += x.y;
    x = bf2x2(g.g[1]); A[2] += x.x; A[3] += x.y;
    x = bf2x2(g.h[0]); A[0] += x.x; A[1] += x.y;
    x = bf2x2(g.h[1]); A[2] += x.x; A[3] += x.y;
}

#define VOFF(s) ((((unsigned)(s)) << 8) + l8)

// ---- paired 2-node aggregation: 16 gathers in flight, single vmcnt(0) ----
// Slots are sentinel-padded (slot n -> zero row), so no masking anywhere.
// Prefetches the NEXT pair's first int4 of slots before the wait.
__device__ inline void agg_pair(const uint2* __restrict__ hs2,
                                const int* __restrict__ bucket,
                                const int* __restrict__ cnt,
                                const float* __restrict__ bias,
                                int nA, int nB, int n, int half, int l32,
                                unsigned l8,
                                int4 saA, int4 saB,
                                const int* __restrict__ pfA,
                                const int* __restrict__ pfB,
                                int4& soA, int4& soB,
                                float4& vA, float4& vB) {
    const int* cpA = bucket + (size_t)min(nA, n - 1) * CAP + half * (CAP / 2);
    const int* cpB = bucket + (size_t)min(nB, n - 1) * CAP + half * (CAP / 2);
    int4 sbA = *(const int4*)(cpA + 4);   // same 128B line as saA: L1 hit
    int4 sbB = *(const int4*)(cpB + 4);
    if (nA >= n) sbA = (int4){n, n, n, n};
    if (nB >= n) sbB = (int4){n, n, n, n};
    int dA = (nA < n) ? cnt[nA] : 0;
    int dB = (nB < n) ? cnt[nB] : 0;
    uint2 suA = hs2[(size_t)min(nA, n - 1) * 32 + l32];
    uint2 suB = hs2[(size_t)min(nB, n - 1) * 32 + l32];

    G8 gA = issue8(hs2, VOFF(saA.x), VOFF(saA.y), VOFF(saA.z), VOFF(saA.w),
                        VOFF(sbA.x), VOFF(sbA.y), VOFF(sbA.z), VOFF(sbA.w));
    G8 gB = issue8(hs2, VOFF(saB.x), VOFF(saB.y), VOFF(saB.z), VOFF(saB.w),
                        VOFF(sbB.x), VOFF(sbB.y), VOFF(sbB.z), VOFF(sbB.w));
    // next pair's slot prefetch: issued before the wait, can't sink below the
    // sched_barrier inside wait_vm0
    int4 tA = *(const int4*)pfA;
    int4 tB = *(const int4*)pfB;
    wait_vm0();
    soA = tA; soB = tB;

    f32x4 A = {0.f, 0.f, 0.f, 0.f};
    consume8(gA, A);
    int chA = (min(dA, CAP) - half + 1) >> 1;
#pragma unroll 1
    for (int k = 8; k < chA; k += 8) {    // rare (P{deg>=17}~10%), sentinel-padded
        int4 xa = *(const int4*)(cpA + k);
        int4 xb = *(const int4*)(cpA + k + 4);
        G8 t = issue8(hs2, VOFF(xa.x), VOFF(xa.y), VOFF(xa.z), VOFF(xa.w),
                           VOFF(xb.x), VOFF(xb.y), VOFF(xb.z), VOFF(xb.w));
        wait_vm0();
        consume8(t, A);
    }
    f32x4 B = {0.f, 0.f, 0.f, 0.f};
    consume8(gB, B);
    int chB = (min(dB, CAP) - half + 1) >> 1;
#pragma unroll 1
    for (int k = 8; k < chB; k += 8) {
        int4 xa = *(const int4*)(cpB + k);
        int4 xb = *(const int4*)(cpB + k + 4);
        G8 t = issue8(hs2, VOFF(xa.x), VOFF(xa.y), VOFF(xa.z), VOFF(xa.w),
                           VOFF(xb.x), VOFF(xb.y), VOFF(xb.z), VOFF(xb.w));
        wait_vm0();
        consume8(t, B);
    }
    if (half == 0) {   // self term (pre-scaled row), counted once
        float2 v0 = bf2x2(suA.x), v1 = bf2x2(suA.y);
        A[0] += v0.x; A[1] += v0.y; A[2] += v1.x; A[3] += v1.y;
        v0 = bf2x2(suB.x); v1 = bf2x2(suB.y);
        B[0] += v0.x; B[1] += v0.y; B[2] += v1.x; B[3] += v1.y;
    }
    float a0 = A[0] + __shfl_xor(A[0], 32);
    float a1 = A[1] + __shfl_xor(A[1], 32);
    float a2 = A[2] + __shfl_xor(A[2], 32);
    float a3 = A[3] + __shfl_xor(A[3], 32);
    float b0 = B[0] + __shfl_xor(B[0], 32);
    float b1 = B[1] + __shfl_xor(B[1], 32);
    float b2 = B[2] + __shfl_xor(B[2], 32);
    float b3 = B[3] + __shfl_xor(B[3], 32);

    vA = (float4){0.f, 0.f, 0.f, 0.f};
    vB = vA;
    if (half == 0) {
        float dnA = rsqrtf((float)dA + 1.0f);
        float dnB = rsqrtf((float)dB + 1.0f);
        float4 bb = *(const float4*)&bias[4 * l32];
        vA.x = fmaxf(dnA * a0 + bb.x, 0.0f);
        vA.y = fmaxf(dnA * a1 + bb.y, 0.0f);
        vA.z = fmaxf(dnA * a2 + bb.z, 0.0f);
        vA.w = fmaxf(dnA * a3 + bb.w, 0.0f);
        vB.x = fmaxf(dnB * b0 + bb.x, 0.0f);
        vB.y = fmaxf(dnB * b1 + bb.y, 0.0f);
        vB.z = fmaxf(dnB * b2 + bb.z, 0.0f);
        vB.w = fmaxf(dnB * b3 + bb.w, 0.0f);
    }
}

// ------- FUSED agg1+GEMM2 (1024 thr): phase A — 16 waves aggregate 4 pairs -------
// ------- each into Xs (LDS); phase B — 16-wave MFMA GEMM -> g2b (distinct). -----
__global__ __launch_bounds__(1024, 8) void k_agg_gemm(
        const uint2* __restrict__ hs2, const int* __restrict__ bucket,
        const int* __restrict__ cnt, const float* __restrict__ bias,
        const unsigned short* __restrict__ Wt, unsigned short* __restrict__ out,
        int n) {
    __shared__ unsigned short Xs[128 * 136];
    __shared__ unsigned short Ws[128 * 136];
    int tid = threadIdx.x;
    int row0 = blockIdx.x * 128;
    int w = tid >> 6;          // 0..15
    int lane = tid & 63;
    int half = lane >> 5;
    int l32 = lane & 31;
    unsigned l8 = (unsigned)l32 * 8u;

    int nb = row0 + w * 8;
    const int* hb = bucket + half * (CAP / 2);
    int4 saA = *(const int4*)(hb + (size_t)min(nb, n - 1) * CAP);
    int4 saB = *(const int4*)(hb + (size_t)min(nb + 1, n - 1) * CAP);
    if (nb     >= n) saA = (int4){n, n, n, n};
    if (nb + 1 >= n) saB = (int4){n, n, n, n};
#pragma unroll 1
    for (int jp = 0; jp < 4; jp++) {
        int nA = nb + 2 * jp, nB = nA + 1;
        int pA = min(nA + 2, n - 1), pB = min(nB + 2, n - 1);
        float4 vA, vB;
        agg_pair(hs2, bucket, cnt, bias, nA, nB, n, half, l32, l8,
                 saA, saB,
                 hb + (size_t)pA * CAP, hb + (size_t)pB * CAP,
                 saA, saB, vA, vB);
        if (nA + 2 >= n) saA = (int4){n, n, n, n};
        if (nB + 2 >= n) saB = (int4){n, n, n, n};
        if (half == 0) {
            ushort4 o;
            o.x = f2bf(vA.x); o.y = f2bf(vA.y); o.z = f2bf(vA.z); o.w = f2bf(vA.w);
            *(ushort4*)&Xs[(w * 8 + 2 * jp) * 136 + 4 * l32] = o;
            o.x = f2bf(vB.x); o.y = f2bf(vB.y); o.z = f2bf(vB.z); o.w = f2bf(vB.w);
            *(ushort4*)&Xs[(w * 8 + 2 * jp + 1) * 136 + 4 * l32] = o;
        }
    }
    // stage Ws
#pragma unroll
    for (int i = 0; i < 2; i++) {
        int c = tid + 1024 * i;
        int r = c >> 4;
        int kc = (c & 15) * 8;
        uint4 v = *(const uint4*)&Wt[r * D + kc];
        *(uint4*)&Ws[r * 136 + kc] = v;
    }
    __syncthreads();

    // phase B: GEMM on the LDS-resident h1 tile
    gemm_compute16(Xs, Ws, cnt, out, n, row0);
}

// ---- FUSED agg2 + BN-stats (512 thr, 1024 blocks, grid-stride node pairs) ----
__global__ __launch_bounds__(512, 6) void k_agg_stats(
        const uint2* __restrict__ hs2, const int* __restrict__ bucket,
        const int* __restrict__ cnt, const float* __restrict__ bias,
        unsigned short* __restrict__ h2, float* __restrict__ S, int N) {
    int tid = threadIdx.x;
    int w = tid >> 6;          // 0..7
    int lane = tid & 63;
    int half = lane >> 5;
    int l32 = lane & 31;
    unsigned l8 = (unsigned)l32 * 8u;
    const int* hb = bucket + half * (CAP / 2);

    float st0 = 0.f, st1 = 0.f, st2 = 0.f, st3 = 0.f;
    float sq0 = 0.f, sq1 = 0.f, sq2 = 0.f, sq3 = 0.f;

    int stride2 = gridDim.x * 16;     // nodes covered per sweep
    int node0 = blockIdx.x * 16 + w * 2;
    int4 saA = *(const int4*)(hb + (size_t)min(node0, N - 1) * CAP);
    int4 saB = *(const int4*)(hb + (size_t)min(node0 + 1, N - 1) * CAP);
    if (node0     >= N) saA = (int4){N, N, N, N};
    if (node0 + 1 >= N) saB = (int4){N, N, N, N};
#pragma unroll 1
    for (int nA = node0; nA < N; nA += stride2) {
        int nB = nA + 1;
        int pA = min(nA + stride2, N - 1);
        int pB = min(nA + stride2 + 1, N - 1);
        float4 vA, vB;
        agg_pair(hs2, bucket, cnt, bias, nA, nB, N, half, l32, l8,
                 saA, saB,
                 hb + (size_t)pA * CAP, hb + (size_t)pB * CAP,
                 saA, saB, vA, vB);
        if (nA + stride2     >= N) saA = (int4){N, N, N, N};
        if (nA + stride2 + 1 >= N) saB = (int4){N, N, N, N};
        if (half == 0) {
            ushort4 o;
            o.x = f2bf(vA.x); o.y = f2bf(vA.y); o.z = f2bf(vA.z); o.w = f2bf(vA.w);
            *(ushort4*)&h2[(size_t)nA * D + 4 * l32] = o;
            st0 += vA.x; st1 += vA.y; st2 += vA.z; st3 += vA.w;
            sq0 += vA.x * vA.x; sq1 += vA.y * vA.y;
            sq2 += vA.z * vA.z; sq3 += vA.w * vA.w;
            if (nB < N) {
                o.x = f2bf(vB.x); o.y = f2bf(vB.y); o.z = f2bf(vB.z); o.w = f2bf(vB.w);
                *(ushort4*)&h2[(size_t)nB * D + 4 * l32] = o;
                st0 += vB.x; st1 += vB.y; st2 += vB.z; st3 += vB.w;
                sq0 += vB.x * vB.x; sq1 += vB.y * vB.y;
                sq2 += vB.z * vB.z; sq3 += vB.w * vB.w;
            }
        }
    }

    __shared__ float sm[8][32][8];
    if (half == 0) {
        sm[w][l32][0] = st0; sm[w][l32][1] = st1;
        sm[w][l32][2] = st2; sm[w][l32][3] = st3;
        sm[w][l32][4] = sq0; sm[w][l32][5] = sq1;
        sm[w][l32][6] = sq2; sm[w][l32][7] = sq3;
    }
    __syncthreads();
    if (tid < D) {
        int f = tid;
        float s = 0.f, q = 0.f;
#pragma unroll
        for (int ww = 0; ww < 8; ww++) {
            s += sm[ww][f >> 2][f & 3];
            q += sm[ww][f >> 2][4 + (f & 3)];
        }
        atomicAdd(&S[f * 16], s);
        atomicAdd(&S[4096 + f * 16], q);
    }
}

// ---------------- BN normalize: bf16 h2 -> f32 out ----------------
__global__ void k_bn(const unsigned* __restrict__ z2, const float* __restrict__ S,
                     const float* __restrict__ gamma, const float* __restrict__ beta,
                     float* __restrict__ out, int N) {
    int i = blockIdx.x * blockDim.x + threadIdx.x;   // uint4 index (8 features)
    int total = N * (D / 8);
    if (i >= total) return;
    int c8 = (i & (D / 8 - 1)) * 8;
    uint4 u = *(const uint4*)&z2[(size_t)i * 4];
    float v[8];
    float2 t;
    t = bf2x2(u.x); v[0] = t.x; v[1] = t.y;
    t = bf2x2(u.y); v[2] = t.x; v[3] = t.y;
    t = bf2x2(u.z); v[4] = t.x; v[5] = t.y;
    t = bf2x2(u.w); v[6] = t.x; v[7] = t.y;
    float invN = 1.0f / (float)N;
    float4 o0, o1;
#pragma unroll
    for (int j = 0; j < 8; j++) {
        float s = S[(c8 + j) * 16];
        float s2 = S[4096 + (c8 + j) * 16];
        float mu = s * invN;
        float iv = rsqrtf(fmaxf(s2 * invN - mu * mu, 0.f) + 1e-5f);
        float val = gamma[c8 + j] * (v[j] - mu) * iv + beta[c8 + j];
        if (j < 4) (&o0.x)[j] = val; else (&o1.x)[j - 4] = val;
    }
    size_t base = (size_t)i * 8;
    *(float4*)&out[base] = o0;
    *(float4*)&out[base + 4] = o1;
}

static inline size_t align_up(size_t x) { return (x + 1023) & ~(size_t)1023; }

extern "C" void kernel_launch(void* const* d_in, const int* in_sizes, int n_in,
                              void* d_out, int out_size, void* d_ws, size_t ws_size,
                              hipStream_t stream) {
    const float* x     = (const float*)d_in[0];
    const int*   ei    = (const int*)d_in[1];
    const float* W1    = (const float*)d_in[2];
    const float* b1    = (const float*)d_in[3];
    const float* W2    = (const float*)d_in[4];
    const float* b2    = (const float*)d_in[5];
    const float* gamma = (const float*)d_in[6];
    const float* beta  = (const float*)d_in[7];

    int N = in_sizes[0] / D;
    int E = in_sizes[1] / 2;
    const int* row = ei;
    const int* col = ei + E;

    char* p = (char*)d_ws;
    int* cnt    = (int*)p;                 // cnt[N] ++ S[8192]: one memset
    float* S    = (float*)(cnt + N);       // strided sums/sumsq, 32KB
    p += align_up((size_t)(N + 8192) * 4);
    int* bucket = (int*)p;   p += align_up((size_t)N * CAP * 4);
    // hsb/g2b have N+1 rows: row N is the zeroed sentinel row
    unsigned short* hsb = (unsigned short*)p; p += align_up((size_t)(N + 1) * D * 2);
    unsigned short* g2b = (unsigned short*)p; p += align_up((size_t)(N + 1) * D * 2);
    unsigned short* h2b = (unsigned short*)p; p += align_up((size_t)N * D * 2);
    unsigned short* Wt1 = (unsigned short*)p; p += align_up((size_t)D * D * 2);
    unsigned short* Wt2 = (unsigned short*)p; p += align_up((size_t)D * D * 2);

    int gemmBlocks = (N + 127) / 128;   // 391
    int fillBlocks = (E + 255) / 256;   // 2344

    hipMemsetAsync(cnt, 0, (size_t)(N + 8192) * 4, stream);
    hipMemsetAsync(hsb + (size_t)N * D, 0, (size_t)D * 2, stream);   // sentinel rows
    hipMemsetAsync(g2b + (size_t)N * D, 0, (size_t)D * 2, stream);
    k_histfill<<<fillBlocks, 256, 0, stream>>>(row, col, cnt, bucket, E,
                                               W1, W2, Wt1, Wt2);
    // layer 1 GEMM (+ bucket sentinel pad)
    k_gemm1<<<gemmBlocks, 1024, 0, stream>>>(x, Wt1, cnt, bucket, hsb, N);
    // fused agg1 + layer 2 GEMM: reads hsb, writes g2b (distinct)
    k_agg_gemm<<<gemmBlocks, 1024, 0, stream>>>((const uint2*)hsb, bucket, cnt, b1,
                                                Wt2, g2b, N);
    // fused layer-2 aggregation + BN stats
    k_agg_stats<<<1024, 512, 0, stream>>>((const uint2*)g2b, bucket, cnt, b2,
                                          h2b, S, N);
    // BN normalize
    k_bn<<<(N * (D / 8) + 255) / 256, 256, 0, stream>>>((const unsigned*)h2b, S,
                                                        gamma, beta, (float*)d_out, N);
}

// Round 5
// 237.334 us; speedup vs baseline: 1.1536x; 1.1536x over previous
//
#include <hip/hip_runtime.h>

// GCN block: h1 = ReLU(Agg(x@W1)+b1); h2 = ReLU(Agg(h1@W2)+b2); out = BN(h2)
// R20: R18's proven single-G8 forced-MLP gather (8 concurrent row gathers,
// one vmcnt(0), no launch_bounds force -> no spills) + R19's sentinel-padded
// buckets (slots [cnt_h, cnt_h+8) point at zeroed row n -> no sanitize
// cndmasks before issue, no masking after the wait, cnt off the critical
// path) + R19's SGPR-base/32-bit-voffset issue8 (8 addr VGPRs, not 16).
// R19's 2-node pairing is dropped: its 32 live dest VGPRs + the (1024,8)
// VGPR cap made the compiler spill G8 state to scratch (VGPR=32,
// WRITE_SIZE 12.5->66MB), serializing the chain through memory.

#define D 128
#define CAP 96   // max in-degree capacity; E/N=12 mean, Poisson tail << 96

typedef __attribute__((ext_vector_type(8))) short bf16x8;
typedef __attribute__((ext_vector_type(4))) float f32x4;
typedef __attribute__((ext_vector_type(2))) unsigned u32x2;

__device__ inline float2 bf2x2(unsigned u) {
    float2 r;
    r.x = __uint_as_float(u << 16);
    r.y = __uint_as_float(u & 0xffff0000u);
    return r;
}
__device__ inline unsigned short f2bf(float f) {
    unsigned u = __float_as_uint(f);
    u += 0x7fffu + ((u >> 16) & 1u);   // round-to-nearest-even
    return (unsigned short)(u >> 16);
}

// ------- fused histogram+fill: one atomic per edge; + W transpose-convert -------
// Split-half bucket layout: slot s -> half s&1, index s>>1 (contiguous per half).
__global__ void k_histfill(const int* __restrict__ row, const int* __restrict__ col,
                           int* __restrict__ cnt, int* __restrict__ bucket, int E,
                           const float* __restrict__ W1, const float* __restrict__ W2,
                           unsigned short* __restrict__ Wt1,
                           unsigned short* __restrict__ Wt2) {
    int e = blockIdx.x * blockDim.x + threadIdx.x;
    if (e < E) {
        int c = col[e];
        int slot = atomicAdd(&cnt[c], 1);
        if (slot < CAP)
            bucket[(size_t)c * CAP + (slot & 1) * (CAP / 2) + (slot >> 1)] = row[e];
    }
    if (blockIdx.x < D) {
        int k = blockIdx.x;
        int t = threadIdx.x;
        if (t < D) Wt1[t * D + k] = f2bf(W1[k * D + t]);
        else       Wt2[(t - D) * D + k] = f2bf(W2[k * D + (t - D)]);
    }
}

// ------ 16-wave GEMM compute: wave w -> m-tile w>>1, n-half w&1 (4 n-tiles) ------
__device__ inline void gemm_compute16(const unsigned short* Xs, const unsigned short* Ws,
                                      const int* __restrict__ cnt,
                                      unsigned short* __restrict__ out, int n, int row0) {
    int tid = threadIdx.x;
    int w = tid >> 6;          // 0..15
    int wm = w >> 1;           // m-tile 0..7
    int wn = w & 1;            // n-half 0..1
    int lane = tid & 63;
    int m16 = lane & 15;
    int quad = lane >> 4;

    f32x4 acc[4];
#pragma unroll
    for (int u = 0; u < 4; u++) acc[u] = (f32x4){0.f, 0.f, 0.f, 0.f};

#pragma unroll
    for (int kc = 0; kc < 4; kc++) {
        bf16x8 a = *(const bf16x8*)&Xs[(wm * 16 + m16) * 136 + kc * 32 + quad * 8];
        bf16x8 b[4];
#pragma unroll
        for (int u = 0; u < 4; u++)
            b[u] = *(const bf16x8*)&Ws[((wn * 4 + u) * 16 + m16) * 136 + kc * 32 + quad * 8];
#pragma unroll
        for (int u = 0; u < 4; u++)
            acc[u] = __builtin_amdgcn_mfma_f32_16x16x32_bf16(a, b[u], acc[u], 0, 0, 0);
    }

    int rbase = row0 + wm * 16 + quad * 4;
#pragma unroll
    for (int i = 0; i < 4; i++) {
        int r = rbase + i;
        if (r < n) {
            float sc = rsqrtf((float)cnt[r] + 1.0f);
#pragma unroll
            for (int u = 0; u < 4; u++)
                out[(size_t)r * D + (wn * 4 + u) * 16 + m16] = f2bf(acc[u][i] * sc);
        }
    }
}

// -- GEMM1 (1024 thr, 16 waves): out[r] = bf16((X @ W)[r] * rsqrt(cnt[r]+1)) --
// Also sentinel-pads the bucket (slots [ch, ch+8) per node-half -> n).
__global__ __launch_bounds__(1024) void k_gemm1(
        const float* __restrict__ Xf, const unsigned short* __restrict__ Wt,
        const int* __restrict__ cnt, int* __restrict__ bucket,
        unsigned short* __restrict__ out, int n) {
    __shared__ unsigned short Xs[128 * 136];   // +8 pad: 2-way banks (free)
    __shared__ unsigned short Ws[128 * 136];
    int tid = threadIdx.x;
    int row0 = blockIdx.x * 128;

#pragma unroll
    for (int i = 0; i < 2; i++) {
        int c = tid + 1024 * i;
        int r = c >> 4;
        int kc = (c & 15) * 8;
        float4 va = {0.f, 0.f, 0.f, 0.f}, vb = {0.f, 0.f, 0.f, 0.f};
        if (row0 + r < n) {
            va = *(const float4*)&Xf[(size_t)(row0 + r) * D + kc];
            vb = *(const float4*)&Xf[(size_t)(row0 + r) * D + kc + 4];
        }
        ushort4 o0, o1;
        o0.x = f2bf(va.x); o0.y = f2bf(va.y); o0.z = f2bf(va.z); o0.w = f2bf(va.w);
        o1.x = f2bf(vb.x); o1.y = f2bf(vb.y); o1.z = f2bf(vb.z); o1.w = f2bf(vb.w);
        *(ushort4*)&Xs[r * 136 + kc] = o0;
        *(ushort4*)&Xs[r * 136 + kc + 4] = o1;
    }
#pragma unroll
    for (int i = 0; i < 2; i++) {
        int c = tid + 1024 * i;
        int r = c >> 4;
        int kc = (c & 15) * 8;
        uint4 v = *(const uint4*)&Wt[r * D + kc];
        *(uint4*)&Ws[r * 136 + kc] = v;
    }
    // sentinel pad: 128 nodes x 16 slot-writes, 2 per thread
#pragma unroll
    for (int q = 0; q < 2; q++) {
        int s = tid * 2 + q;
        int nl = s >> 4, sl = s & 15;
        int node = row0 + nl;
        if (node < n) {
            int mm = min(cnt[node], CAP);
            int hf = sl >> 3, kk = sl & 7;
            int j = ((mm - hf + 1) >> 1) + kk;
            if (j < CAP / 2)
                bucket[(size_t)node * CAP + hf * (CAP / 2) + j] = n;
        }
    }
    __syncthreads();
    gemm_compute16(Xs, Ws, cnt, out, n, row0);
}

// ---- forced-MLP gather: 8 concurrent row gathers (issue only, no wait) ----
struct G8 { u32x2 a, b, c, d, e, f, g, h; };

__device__ inline G8 issue8(const uint2* __restrict__ hs2,
                            unsigned o0, unsigned o1, unsigned o2, unsigned o3,
                            unsigned o4, unsigned o5, unsigned o6, unsigned o7) {
    G8 r;
    asm volatile(
        "global_load_dwordx2 %0, %8, %16\n\t"
        "global_load_dwordx2 %1, %9, %16\n\t"
        "global_load_dwordx2 %2, %10, %16\n\t"
        "global_load_dwordx2 %3, %11, %16\n\t"
        "global_load_dwordx2 %4, %12, %16\n\t"
        "global_load_dwordx2 %5, %13, %16\n\t"
        "global_load_dwordx2 %6, %14, %16\n\t"
        "global_load_dwordx2 %7, %15, %16"
        : "=&v"(r.a), "=&v"(r.b), "=&v"(r.c), "=&v"(r.d),
          "=&v"(r.e), "=&v"(r.f), "=&v"(r.g), "=&v"(r.h)
        : "v"(o0), "v"(o1), "v"(o2), "v"(o3),
          "v"(o4), "v"(o5), "v"(o6), "v"(o7),
          "s"(hs2));
    return r;
}

__device__ inline void wait_vm0() {
    asm volatile("s_waitcnt vmcnt(0)" ::: "memory");
    __builtin_amdgcn_sched_barrier(0);   // keep consumers below (rule: hipcc
                                         // hoists reg-only ops past asm waits)
}

__device__ inline void consume8(const G8& g, f32x4& A) {
    float2 x;
    x = bf2x2(g.a[0]); A[0] += x.x; A[1] += x.y;
    x = bf2x2(g.a[1]); A[2] += x.x; A[3] += x.y;
    x = bf2x2(g.b[0]); A[0] += x.x; A[1] += x.y;
    x = bf2x2(g.b[1]); A[2] += x.x; A[3] += x.y;
    x = bf2x2(g.c[0]); A[0] += x.x; A[1] += x.y;
    x = bf2x2(g.c[1]); A[2] += x.x; A[3] += x.y;
    x = bf2x2(g.d[0]); A[0] += x.x; A[1] += x.y;
    x = bf2x2(g.d[1]); A[2] += x.x; A[3] += x.y;
    x = bf2x2(g.e[0]); A[0] += x.x; A[1] += x.y;
    x = bf2x2(g.e[1]); A[2] += x.x; A[3] += x.y;
    x = bf2x2(g.f[0]); A[0] += x.x; A[1] += x.y;
    x = bf2x2(g.f[1]); A[2] += x.x; A[3] += x.y;
    x = bf2x2(g.g[0]); A[0] += x.x; A[1] += x.y;
    x = bf2x2(g.g[1]); A[2] += x.x; A[3] += x.y;
    x = bf2x2(g.h[0]); A[0] += x.x; A[1] += x.y;
    x = bf2x2(g.h[1]); A[2] += x.x; A[3] += x.y;
}

#define VOFF(s) ((((unsigned)(s)) << 8) + l8)

// ---- device agg for one node; half-0 lanes return float4 (bias+ReLU applied) ----
// Buckets are sentinel-padded (slot n -> zeroed row): no sanitize, no masking.
// Caller prefetches next node's slots+cnt before this call (overlaps the wait).
__device__ inline float4 agg_node_f(const uint2* __restrict__ hs2,
                                    const int* __restrict__ cp, int dcnt,
                                    int4 sa, int4 sb,
                                    const float* __restrict__ bias,
                                    int node, int half, int l32, unsigned l8) {
    uint2 su = hs2[(size_t)node * 32 + l32];   // self row; same vmcnt window
    G8 g = issue8(hs2, VOFF(sa.x), VOFF(sa.y), VOFF(sa.z), VOFF(sa.w),
                       VOFF(sb.x), VOFF(sb.y), VOFF(sb.z), VOFF(sb.w));
    wait_vm0();
    f32x4 A = {0.f, 0.f, 0.f, 0.f};
    consume8(g, A);
    int ch = (min(dcnt, CAP) - half + 1) >> 1;
#pragma unroll 1
    for (int k = 8; k < ch; k += 8) {   // rare tail (deg >= 17), sentinel-padded
        int4 xa = *(const int4*)(cp + k);
        int4 xb = *(const int4*)(cp + k + 4);
        G8 t = issue8(hs2, VOFF(xa.x), VOFF(xa.y), VOFF(xa.z), VOFF(xa.w),
                           VOFF(xb.x), VOFF(xb.y), VOFF(xb.z), VOFF(xb.w));
        wait_vm0();
        consume8(t, A);
    }
    if (half == 0) {   // self term (pre-scaled row)
        float2 v0 = bf2x2(su.x), v1 = bf2x2(su.y);
        A[0] += v0.x; A[1] += v0.y; A[2] += v1.x; A[3] += v1.y;
    }
    float a0 = A[0] + __shfl_xor(A[0], 32);
    float a1 = A[1] + __shfl_xor(A[1], 32);
    float a2 = A[2] + __shfl_xor(A[2], 32);
    float a3 = A[3] + __shfl_xor(A[3], 32);

    float4 o = {0.f, 0.f, 0.f, 0.f};
    if (half == 0) {
        float dn = rsqrtf((float)dcnt + 1.0f);
        float4 b = *(const float4*)&bias[4 * l32];
        o.x = fmaxf(dn * a0 + b.x, 0.0f);
        o.y = fmaxf(dn * a1 + b.y, 0.0f);
        o.z = fmaxf(dn * a2 + b.z, 0.0f);
        o.w = fmaxf(dn * a3 + b.w, 0.0f);
    }
    return o;
}

// ------- FUSED agg1+GEMM2 (1024 thr): phase A — 16 waves aggregate 8 nodes -------
// ------- each into Xs (LDS); phase B — 16-wave MFMA GEMM -> g2b (distinct). -----
__global__ __launch_bounds__(1024) void k_agg_gemm(
        const uint2* __restrict__ hs2, const int* __restrict__ bucket,
        const int* __restrict__ cnt, const float* __restrict__ bias,
        const unsigned short* __restrict__ Wt, unsigned short* __restrict__ out,
        int n) {
    __shared__ unsigned short Xs[128 * 136];
    __shared__ unsigned short Ws[128 * 136];
    int tid = threadIdx.x;
    int row0 = blockIdx.x * 128;
    int w = tid >> 6;          // 0..15
    int lane = tid & 63;
    int half = lane >> 5;
    int l32 = lane & 31;
    unsigned l8 = (unsigned)l32 * 8u;
    const int* hb = bucket + half * (CAP / 2);

    // phase A: wave w aggregates nodes row0 + w*8 + j, j=0..7 (slot/cnt pipelined)
    int nb = row0 + w * 8;
    const int* cp = hb + (size_t)min(nb, n - 1) * CAP;
    int4 sa = *(const int4*)cp;
    int4 sb = *(const int4*)(cp + 4);
    int dcnt = cnt[min(nb, n - 1)];
#pragma unroll 1
    for (int j = 0; j < 8; j++) {
        int node = nb + j;
        // prefetch next node's slots + cnt (issued before the gather wait)
        int nn = min(node + 1, n - 1);
        const int* cpn = hb + (size_t)nn * CAP;
        int4 sa_n = *(const int4*)cpn;
        int4 sb_n = *(const int4*)(cpn + 4);
        int dc_n = cnt[nn];
        float4 v = {0.f, 0.f, 0.f, 0.f};
        if (node < n)
            v = agg_node_f(hs2, cp, dcnt, sa, sb, bias, node, half, l32, l8);
        if (half == 0) {
            ushort4 o;
            o.x = f2bf(v.x); o.y = f2bf(v.y); o.z = f2bf(v.z); o.w = f2bf(v.w);
            *(ushort4*)&Xs[(w * 8 + j) * 136 + 4 * l32] = o;
        }
        cp = cpn; sa = sa_n; sb = sb_n; dcnt = dc_n;
    }
    // stage Ws
#pragma unroll
    for (int i = 0; i < 2; i++) {
        int c = tid + 1024 * i;
        int r = c >> 4;
        int kc = (c & 15) * 8;
        uint4 v = *(const uint4*)&Wt[r * D + kc];
        *(uint4*)&Ws[r * 136 + kc] = v;
    }
    __syncthreads();

    // phase B: GEMM on the LDS-resident h1 tile
    gemm_compute16(Xs, Ws, cnt, out, n, row0);
}

// ---- FUSED agg2 + BN-stats (1024 thr, 512 blocks, grid-stride over nodes) ----
__global__ __launch_bounds__(1024) void k_agg_stats(
        const uint2* __restrict__ hs2, const int* __restrict__ bucket,
        const int* __restrict__ cnt, const float* __restrict__ bias,
        unsigned short* __restrict__ h2, float* __restrict__ S, int N) {
    int tid = threadIdx.x;
    int w = tid >> 6;
    int lane = tid & 63;
    int half = lane >> 5;
    int l32 = lane & 31;
    unsigned l8 = (unsigned)l32 * 8u;
    const int* hb = bucket + half * (CAP / 2);

    float st0 = 0.f, st1 = 0.f, st2 = 0.f, st3 = 0.f;
    float sq0 = 0.f, sq1 = 0.f, sq2 = 0.f, sq3 = 0.f;

    int stride = gridDim.x * 16;
    int node = blockIdx.x * 16 + w;
    int4 sa = {0, 0, 0, 0}, sb = {0, 0, 0, 0};
    int dcnt = 0;
    if (node < N) {
        const int* cp0 = hb + (size_t)node * CAP;
        sa = *(const int4*)cp0;
        sb = *(const int4*)(cp0 + 4);
        dcnt = cnt[node];
    }
#pragma unroll 1
    for (; node < N; node += stride) {
        // prefetch next grid-stride node's slots + cnt (overlaps the wait)
        int nn = min(node + stride, N - 1);
        const int* cpn = hb + (size_t)nn * CAP;
        int4 sa_n = *(const int4*)cpn;
        int4 sb_n = *(const int4*)(cpn + 4);
        int dc_n = cnt[nn];
        const int* cp = hb + (size_t)node * CAP;
        float4 v = agg_node_f(hs2, cp, dcnt, sa, sb, bias, node, half, l32, l8);
        if (half == 0) {
            ushort4 o;
            o.x = f2bf(v.x); o.y = f2bf(v.y); o.z = f2bf(v.z); o.w = f2bf(v.w);
            *(ushort4*)&h2[(size_t)node * D + 4 * l32] = o;
            st0 += v.x; st1 += v.y; st2 += v.z; st3 += v.w;
            sq0 += v.x * v.x; sq1 += v.y * v.y;
            sq2 += v.z * v.z; sq3 += v.w * v.w;
        }
        sa = sa_n; sb = sb_n; dcnt = dc_n;
    }

    __shared__ float sm[16][32][8];
    if (half == 0) {
        sm[w][l32][0] = st0; sm[w][l32][1] = st1;
        sm[w][l32][2] = st2; sm[w][l32][3] = st3;
        sm[w][l32][4] = sq0; sm[w][l32][5] = sq1;
        sm[w][l32][6] = sq2; sm[w][l32][7] = sq3;
    }
    __syncthreads();
    if (tid < D) {
        int f = tid;
        float s = 0.f, q = 0.f;
#pragma unroll
        for (int ww = 0; ww < 16; ww++) {
            s += sm[ww][f >> 2][f & 3];
            q += sm[ww][f >> 2][4 + (f & 3)];
        }
        atomicAdd(&S[f * 16], s);
        atomicAdd(&S[4096 + f * 16], q);
    }
}

// ---------------- BN normalize: bf16 h2 -> f32 out ----------------
__global__ void k_bn(const unsigned* __restrict__ z2, const float* __restrict__ S,
                     const float* __restrict__ gamma, const float* __restrict__ beta,
                     float* __restrict__ out, int N) {
    int i = blockIdx.x * blockDim.x + threadIdx.x;   // uint4 index (8 features)
    int total = N * (D / 8);
    if (i >= total) return;
    int c8 = (i & (D / 8 - 1)) * 8;
    uint4 u = *(const uint4*)&z2[(size_t)i * 4];
    float v[8];
    float2 t;
    t = bf2x2(u.x); v[0] = t.x; v[1] = t.y;
    t = bf2x2(u.y); v[2] = t.x; v[3] = t.y;
    t = bf2x2(u.z); v[4] = t.x; v[5] = t.y;
    t = bf2x2(u.w); v[6] = t.x; v[7] = t.y;
    float invN = 1.0f / (float)N;
    float4 o0, o1;
#pragma unroll
    for (int j = 0; j < 8; j++) {
        float s = S[(c8 + j) * 16];
        float s2 = S[4096 + (c8 + j) * 16];
        float mu = s * invN;
        float iv = rsqrtf(fmaxf(s2 * invN - mu * mu, 0.f) + 1e-5f);
        float val = gamma[c8 + j] * (v[j] - mu) * iv + beta[c8 + j];
        if (j < 4) (&o0.x)[j] = val; else (&o1.x)[j - 4] = val;
    }
    size_t base = (size_t)i * 8;
    *(float4*)&out[base] = o0;
    *(float4*)&out[base + 4] = o1;
}

static inline size_t align_up(size_t x) { return (x + 1023) & ~(size_t)1023; }

extern "C" void kernel_launch(void* const* d_in, const int* in_sizes, int n_in,
                              void* d_out, int out_size, void* d_ws, size_t ws_size,
                              hipStream_t stream) {
    const float* x     = (const float*)d_in[0];
    const int*   ei    = (const int*)d_in[1];
    const float* W1    = (const float*)d_in[2];
    const float* b1    = (const float*)d_in[3];
    const float* W2    = (const float*)d_in[4];
    const float* b2    = (const float*)d_in[5];
    const float* gamma = (const float*)d_in[6];
    const float* beta  = (const float*)d_in[7];

    int N = in_sizes[0] / D;
    int E = in_sizes[1] / 2;
    const int* row = ei;
    const int* col = ei + E;

    char* p = (char*)d_ws;
    int* cnt    = (int*)p;                 // cnt[N] ++ S[8192]: one memset
    float* S    = (float*)(cnt + N);       // strided sums/sumsq, 32KB
    p += align_up((size_t)(N + 8192) * 4);
    int* bucket = (int*)p;   p += align_up((size_t)N * CAP * 4);
    // hsb/g2b have N+1 rows: row N is the zeroed sentinel row
    unsigned short* hsb = (unsigned short*)p; p += align_up((size_t)(N + 1) * D * 2);
    unsigned short* g2b = (unsigned short*)p; p += align_up((size_t)(N + 1) * D * 2);
    unsigned short* h2b = (unsigned short*)p; p += align_up((size_t)N * D * 2);
    unsigned short* Wt1 = (unsigned short*)p; p += align_up((size_t)D * D * 2);
    unsigned short* Wt2 = (unsigned short*)p; p += align_up((size_t)D * D * 2);

    int gemmBlocks = (N + 127) / 128;   // 391
    int fillBlocks = (E + 255) / 256;   // 2344

    hipMemsetAsync(cnt, 0, (size_t)(N + 8192) * 4, stream);
    hipMemsetAsync(hsb + (size_t)N * D, 0, (size_t)D * 2, stream);   // sentinel rows
    hipMemsetAsync(g2b + (size_t)N * D, 0, (size_t)D * 2, stream);
    k_histfill<<<fillBlocks, 256, 0, stream>>>(row, col, cnt, bucket, E,
                                               W1, W2, Wt1, Wt2);
    // layer 1 GEMM (+ bucket sentinel pad)
    k_gemm1<<<gemmBlocks, 1024, 0, stream>>>(x, Wt1, cnt, bucket, hsb, N);
    // fused agg1 + layer 2 GEMM: reads hsb, writes g2b (distinct)
    k_agg_gemm<<<gemmBlocks, 1024, 0, stream>>>((const uint2*)hsb, bucket, cnt, b1,
                                                Wt2, g2b, N);
    // fused layer-2 aggregation + BN stats
    k_agg_stats<<<512, 1024, 0, stream>>>((const uint2*)g2b, bucket, cnt, b2,
                                          h2b, S, N);
    // BN normalize
    k_bn<<<(N * (D / 8) + 255) / 256, 256, 0, stream>>>((const unsigned*)h2b, S,
                                                        gamma, beta, (float*)d_out, N);
}